// Round 7
// baseline (1596.221 us; speedup 1.0000x reference)
//
#include <hip/hip_runtime.h>
#include <stdint.h>
#include <stddef.h>

#define DH 128

static __device__ __forceinline__ float bf2f(uint16_t h) {
    union { uint32_t i; float f; } u; u.i = ((uint32_t)h) << 16; return u.f;
}
static __device__ __forceinline__ uint16_t f2bf(float f) {
    union { float f; uint32_t i; } u; u.f = f;
    uint32_t r = u.i + 0x7fffu + ((u.i >> 16) & 1u);  // RNE
    return (uint16_t)(r >> 16);
}

// ---------- dtype detection: is w_l0 fp32 or bf16? ----------
// If the buffer holds bf16 pairs, the LOW u16 of each u32 is a bf16 weight
// (|w|~0.05) whose exponent field lands in [100,130] nearly always. If it
// holds fp32, the low u16 is mantissa noise -> exponent field uniform
// (P(hit) ~ 12%). 256 samples, threshold 128: unambiguous.
__global__ void detect_k(const uint32_t* w, int* flag) {
    int t = threadIdx.x;
    int hits = 0;
    for (int k = 0; k < 4; ++k) {
        uint32_t u = w[t * 4 + k];
        int e = (u >> 7) & 0xFF;
        hits += (e >= 100 && e <= 130) ? 1 : 0;
    }
    for (int off = 32; off; off >>= 1) hits += __shfl_down(hits, off);
    if (t == 0) *flag = (hits >= 128) ? 0 : 1;   // 0 = bf16, 1 = fp32
}

static __device__ __forceinline__ float loadf(const void* p, size_t i, bool f32) {
    return f32 ? ((const float*)p)[i] : bf2f(((const uint16_t*)p)[i]);
}

// ---------- CSR build ----------
__global__ void zero_cnt_k(int* cnt, int n) {
    int i = blockIdx.x * 256 + threadIdx.x;
    if (i < n) cnt[i] = 0;
}

__global__ void count_k(const int* dst, int* cnt, int E, int n) {
    int e = blockIdx.x * 256 + threadIdx.x;
    if (e < E) {
        int d = dst[e];
        if ((unsigned)d < (unsigned)n) atomicAdd(&cnt[d], 1);
    }
}

__global__ void scan_k(const int* cnt, int* row_start, int* cursor,
                       float* inv_deg, int n) {
    __shared__ int wt[4];
    __shared__ int carry_s;
    int t = threadIdx.x, lane = t & 63, wv = t >> 6;
    if (t == 0) carry_s = 0;
    __syncthreads();
    for (int base = 0; base < n; base += 256) {
        int i = base + t;
        int c = (i < n) ? cnt[i] : 0;
        int v = c;
        for (int off = 1; off < 64; off <<= 1) {
            int u = __shfl_up(v, off);
            if (lane >= off) v += u;
        }
        if (lane == 63) wt[wv] = v;
        __syncthreads();
        int woff = 0;
        for (int w = 0; w < wv; ++w) woff += wt[w];
        int total = wt[0] + wt[1] + wt[2] + wt[3];
        int carry = carry_s;
        if (i < n) {
            int rs = carry + woff + (v - c);
            row_start[i] = rs;
            cursor[i] = rs;
            inv_deg[i] = 1.0f / fmaxf((float)c, 1.0f);
        }
        __syncthreads();
        if (t == 0) carry_s = carry + total;
        __syncthreads();
    }
    if (t == 0) row_start[n] = carry_s;
}

__global__ void fill_k(const int* src, const int* dst, int* cursor,
                       int* csr_src, int E, int n) {
    int e = blockIdx.x * 256 + threadIdx.x;
    if (e < E) {
        int d = dst[e];
        if ((unsigned)d < (unsigned)n) {
            int pos = atomicAdd(&cursor[d], 1);
            csr_src[pos] = src[e];
        }
    }
}

// ---------- mean aggregation: one wave per dst node ----------
// feat is dual-dtype (dt!=null: branch on flag); A output always bf16.
__global__ void agg_k(const void* feat, const int* dt, const int* csr_src,
                      const int* row_start, const float* inv_deg,
                      uint16_t* A, int n) {
    int wave = threadIdx.x >> 6, lane = threadIdx.x & 63;
    int node = blockIdx.x * 4 + wave;
    if (node >= n) return;
    bool f32 = (dt != nullptr) && (*dt != 0);
    int e0 = row_start[node], e1 = row_start[node + 1];
    float ax = 0.f, ay = 0.f;
    if (f32) {
        const float2* fp = (const float2*)feat;
        for (int e = e0; e < e1; ++e) {
            int s = csr_src[e];
            if ((unsigned)s >= (unsigned)n) continue;
            float2 v = fp[(size_t)s * 64 + lane];
            ax += v.x; ay += v.y;
        }
    } else {
        const uint32_t* fp = (const uint32_t*)feat;
        for (int e = e0; e < e1; ++e) {
            int s = csr_src[e];
            if ((unsigned)s >= (unsigned)n) continue;
            uint32_t u = fp[(size_t)s * 64 + lane];
            ax += bf2f((uint16_t)u);
            ay += bf2f((uint16_t)(u >> 16));
        }
    }
    float sc = inv_deg[node];
    uint32_t w = (uint32_t)f2bf(ax * sc) | ((uint32_t)f2bf(ay * sc) << 16);
    ((uint32_t*)A)[(size_t)node * 64 + lane] = w;
}

// ---------- dense: Y = X@W^T (+bias, +root, relu) — 24 KB LDS, K-chunked ----------
// X dual-dtype via xdt (null = bf16 internal buffer); W/bias dual via wdt.
// Hroot/Y always bf16 internal. In-place safe for X==Y.
__global__ void dense_k(const void* __restrict__ X, const int* xdt,
                        const void* __restrict__ W, const int* wdt,
                        const void* __restrict__ bias,
                        uint16_t* __restrict__ Hroot,
                        uint16_t* __restrict__ Y, int n) {
    __shared__ float wa[16 * 128];     // 8 KB
    __shared__ float wb[16 * 128];     // 8 KB
    __shared__ float xlds[64 * 32];    // 8 KB
    const int tid = threadIdx.x;
    const int o = tid & 127, which = tid >> 7;
    const int base = blockIdx.x * 64;
    const bool xf32 = (xdt != nullptr) && (*xdt != 0);
    const bool wf32 = (*wdt != 0);

    float b = 0.0f;
    if (bias != nullptr) b = loadf(bias, o, wf32);
    float acc[32];
#pragma unroll
    for (int j = 0; j < 32; ++j) acc[j] = b;

    for (int kc = 0; kc < 4; ++kc) {
        __syncthreads();
        for (int g = tid; g < 2048; g += 256) {
            int row = g >> 4, i = g & 15;
            float lo, hi;
            if (wf32) {
                const float* Wf = (const float*)W;
                lo = Wf[row * 128 + kc * 32 + 2 * i];
                hi = Wf[row * 128 + kc * 32 + 2 * i + 1];
            } else {
                uint32_t u = ((const uint32_t*)W)[row * 64 + kc * 16 + i];
                lo = bf2f((uint16_t)u);
                hi = bf2f((uint16_t)(u >> 16));
            }
            wa[i * 128 + row] = lo;
            wb[i * 128 + row] = hi;
        }
        for (int g = tid; g < 1024; g += 256) {
            int node = g >> 4, i = g & 15;
            int gn = base + node;
            float lo = 0.f, hi = 0.f;
            if (gn < n) {
                if (xf32) {
                    const float* Xf = (const float*)X;
                    lo = Xf[(size_t)gn * 128 + kc * 32 + 2 * i];
                    hi = Xf[(size_t)gn * 128 + kc * 32 + 2 * i + 1];
                } else {
                    uint32_t u = ((const uint32_t*)X)[(size_t)gn * 64 + kc * 16 + i];
                    lo = bf2f((uint16_t)u);
                    hi = bf2f((uint16_t)(u >> 16));
                }
            }
            xlds[node * 32 + 2 * i]     = lo;
            xlds[node * 32 + 2 * i + 1] = hi;
        }
        __syncthreads();
#pragma unroll
        for (int j = 0; j < 32; ++j) {
            const float* xr = &xlds[(which * 32 + j) * 32];
            float a = acc[j];
#pragma unroll
            for (int i = 0; i < 16; ++i) {
                a += xr[2 * i]     * wa[i * 128 + o];
                a += xr[2 * i + 1] * wb[i * 128 + o];
            }
            acc[j] = a;
        }
    }
#pragma unroll
    for (int j = 0; j < 32; ++j) {
        int node = base + which * 32 + j;
        if (node < n) {
            size_t idx = (size_t)node * DH + o;
            float v = acc[j];
            if (Hroot != nullptr) {
                v += bf2f(Hroot[idx]);
                Hroot[idx] = f2bf(fmaxf(v, 0.0f));
            } else {
                Y[idx] = f2bf(v);
            }
        }
    }
}

// ---------- layer 2: transform-then-aggregate (linearity of mean) ----------
__global__ void transform2_k(const uint16_t* H, const void* Wl2,
                             const void* Wr2, const int* wdt,
                             float* T, float* Q, int n) {
    int wave = threadIdx.x >> 6, lane = threadIdx.x & 63;
    int node = blockIdx.x * 4 + wave;
    if (node >= n) return;
    bool f32 = (*wdt != 0);
    const uint16_t* h = H + (size_t)node * DH;
    float h0 = bf2f(h[lane]), h1 = bf2f(h[lane + 64]);
    float p0 = h0 * loadf(Wl2, lane, f32)       + h1 * loadf(Wl2, 64 + lane, f32);
    float p1 = h0 * loadf(Wl2, 128 + lane, f32) + h1 * loadf(Wl2, 192 + lane, f32);
    float q0 = h0 * loadf(Wr2, lane, f32)       + h1 * loadf(Wr2, 64 + lane, f32);
    float q1 = h0 * loadf(Wr2, 128 + lane, f32) + h1 * loadf(Wr2, 192 + lane, f32);
    for (int off = 32; off; off >>= 1) {
        p0 += __shfl_down(p0, off);
        p1 += __shfl_down(p1, off);
        q0 += __shfl_down(q0, off);
        q1 += __shfl_down(q1, off);
    }
    if (lane == 0) {
        T[(size_t)node * 2]     = p0;
        T[(size_t)node * 2 + 1] = p1;
        Q[(size_t)node * 2]     = q0;
        Q[(size_t)node * 2 + 1] = q1;
    }
}

// ---------- final: 2-wide CSR gather + log_softmax, fp32 out ----------
__global__ void final_k(const float* T, const float* Q, const int* row_start,
                        const int* csr_src, const float* inv_deg,
                        const void* b2, const int* wdt, float* out, int n) {
    int i = blockIdx.x * 256 + threadIdx.x;
    if (i >= n) return;
    bool f32 = (*wdt != 0);
    int e0 = row_start[i], e1 = row_start[i + 1];
    float s0 = 0.f, s1 = 0.f;
    for (int e = e0; e < e1; ++e) {
        int j = csr_src[e];
        if ((unsigned)j >= (unsigned)n) continue;
        s0 += T[(size_t)j * 2];
        s1 += T[(size_t)j * 2 + 1];
    }
    float sc = inv_deg[i];
    float l0 = s0 * sc + loadf(b2, 0, f32) + Q[(size_t)i * 2];
    float l1 = s1 * sc + loadf(b2, 1, f32) + Q[(size_t)i * 2 + 1];
    float m = fmaxf(l0, l1);
    float lse = m + logf(expf(l0 - m) + expf(l1 - m));
    out[(size_t)i * 2]     = l0 - lse;
    out[(size_t)i * 2 + 1] = l1 - lse;
}

extern "C" void kernel_launch(void* const* d_in, const int* in_sizes, int n_in,
                              void* d_out, int out_size, void* d_ws, size_t ws_size,
                              hipStream_t stream) {
    // Insertion (documented) vs sorted-keys order, discriminated by in_sizes[0].
    int ix, iwl0, ib0, iwr0, iwl1, ib1, iwr1, iwl2, ib2, iwr2, iesrc, iedst;
    if (in_sizes[0] < 100000) {  // sorted keys: b0,b1,b2,edge_dst,edge_src,w_l0..w_l2,w_r0..w_r2,x
        ib0 = 0; ib1 = 1; ib2 = 2; iedst = 3; iesrc = 4;
        iwl0 = 5; iwl1 = 6; iwl2 = 7; iwr0 = 8; iwr1 = 9; iwr2 = 10; ix = 11;
    } else {                     // dict-insertion order (documented contract)
        ix = 0; iwl0 = 1; ib0 = 2; iwr0 = 3; iwl1 = 4; ib1 = 5;
        iwr1 = 6; iwl2 = 7; ib2 = 8; iwr2 = 9; iesrc = 10; iedst = 11;
    }
    const void* x   = d_in[ix];
    const void* wl0 = d_in[iwl0];
    const void* b0  = d_in[ib0];
    const void* wr0 = d_in[iwr0];
    const void* wl1 = d_in[iwl1];
    const void* b1  = d_in[ib1];
    const void* wr1 = d_in[iwr1];
    const void* wl2 = d_in[iwl2];
    const void* b2  = d_in[ib2];
    const void* wr2 = d_in[iwr2];
    const int* esrc = (const int*)d_in[iesrc];
    const int* edst = (const int*)d_in[iedst];
    const int N = out_size / 2;          // output is [N,2] fp32
    const int E = in_sizes[iesrc];
    (void)n_in; (void)ws_size; (void)b1;

    char* ws = (char*)d_ws;
    size_t off = 0;
    int* dtf = (int*)(ws + off);          off += 256;
    int* cnt = (int*)(ws + off);          off += (size_t)N * 4;       off = (off + 255) & ~(size_t)255;
    int* row_start = (int*)(ws + off);    off += (size_t)(N + 1) * 4; off = (off + 255) & ~(size_t)255;
    int* cursor = (int*)(ws + off);       off += (size_t)N * 4;       off = (off + 255) & ~(size_t)255;
    float* inv_deg = (float*)(ws + off);  off += (size_t)N * 4;       off = (off + 255) & ~(size_t)255;
    int* csr_src = (int*)(ws + off);      off += (size_t)E * 4;       off = (off + 255) & ~(size_t)255;
    uint16_t* A16 = (uint16_t*)(ws + off); off += (size_t)N * DH * 2; off = (off + 255) & ~(size_t)255;
    uint16_t* H16 = (uint16_t*)(ws + off); off += (size_t)N * DH * 2; off = (off + 255) & ~(size_t)255;
    float* T = (float*)(ws + off);        off += (size_t)N * 2 * 4;   off = (off + 255) & ~(size_t)255;
    float* Q = (float*)(ws + off);        off += (size_t)N * 2 * 4;

    int gN = (N + 255) / 256;
    int gE = (E + 255) / 256;
    int ga = (N + 3) / 4;
    int gd = (N + 63) / 64;

    // dtype detection (flag in workspace; all later kernels branch on it)
    detect_k<<<1, 64, 0, stream>>>((const uint32_t*)wl0, dtf);

    // CSR build
    zero_cnt_k<<<gN, 256, 0, stream>>>(cnt, N);
    count_k<<<gE, 256, 0, stream>>>(edst, cnt, E, N);
    scan_k<<<1, 256, 0, stream>>>(cnt, row_start, cursor, inv_deg, N);
    fill_k<<<gE, 256, 0, stream>>>(esrc, edst, cursor, csr_src, E, N);

    // layer 0: A = agg(x); H = x@Wr0^T; H = relu(A@Wl0^T + b0 + H)
    agg_k<<<ga, 256, 0, stream>>>(x, dtf, csr_src, row_start, inv_deg, A16, N);
    dense_k<<<gd, 256, 0, stream>>>(x, dtf, wr0, dtf, nullptr, nullptr, H16, N);
    dense_k<<<gd, 256, 0, stream>>>(A16, nullptr, wl0, dtf, b0, H16, nullptr, N);

    // layer 1: A = agg(H); H = H@Wr1^T (in-place); H = relu(A@Wl1^T + b1 + H)
    agg_k<<<ga, 256, 0, stream>>>(H16, nullptr, csr_src, row_start, inv_deg, A16, N);
    dense_k<<<gd, 256, 0, stream>>>(H16, nullptr, wr1, dtf, nullptr, nullptr, H16, N);
    dense_k<<<gd, 256, 0, stream>>>(A16, nullptr, wl1, dtf, b1, H16, nullptr, N);

    // layer 2: transform-then-aggregate + log_softmax (fp32 out)
    transform2_k<<<ga, 256, 0, stream>>>(H16, wl2, wr2, dtf, T, Q, N);
    final_k<<<gN, 256, 0, stream>>>(T, Q, row_start, csr_src, inv_deg,
                                    b2, dtf, (float*)d_out, N);
}

// Round 8
// 833.768 us; speedup vs baseline: 1.9145x; 1.9145x over previous
//
#include <hip/hip_runtime.h>
#include <stdint.h>
#include <stddef.h>

#define DH 128

typedef short v8s __attribute__((ext_vector_type(8)));
typedef float v4f __attribute__((ext_vector_type(4)));

static __device__ __forceinline__ float bf2f(uint16_t h) {
    union { uint32_t i; float f; } u; u.i = ((uint32_t)h) << 16; return u.f;
}
static __device__ __forceinline__ uint16_t f2bf(float f) {
    union { float f; uint32_t i; } u; u.f = f;
    uint32_t r = u.i + 0x7fffu + ((u.i >> 16) & 1u);  // RNE
    return (uint16_t)(r >> 16);
}

// ---------- dtype detection (unchanged — round 7 passed with it) ----------
__global__ void detect_k(const uint32_t* w, int* flag) {
    int t = threadIdx.x;
    int hits = 0;
    for (int k = 0; k < 4; ++k) {
        uint32_t u = w[t * 4 + k];
        int e = (u >> 7) & 0xFF;
        hits += (e >= 100 && e <= 130) ? 1 : 0;
    }
    for (int off = 32; off; off >>= 1) hits += __shfl_down(hits, off);
    if (t == 0) *flag = (hits >= 128) ? 0 : 1;   // 0 = bf16, 1 = fp32
}

static __device__ __forceinline__ float loadf(const void* p, size_t i, bool f32) {
    return f32 ? ((const float*)p)[i] : bf2f(((const uint16_t*)p)[i]);
}

// ---------- dtype normalization: everything dense-path becomes bf16 ----------
__global__ void cvt_k(const void* src, const int* dt, uint16_t* dst, int n) {
    int i = blockIdx.x * 256 + threadIdx.x;
    if (i >= n) return;
    bool f32 = (*dt != 0);
    dst[i] = f32 ? f2bf(((const float*)src)[i]) : ((const uint16_t*)src)[i];
}

// 4 weights [128x128] + 2 biases [128] packed into one output buffer
__global__ void cvtw_k(const void* wl0, const void* wr0, const void* wl1,
                       const void* wr1, const void* b0, const void* b1,
                       const int* dt, uint16_t* out) {
    int i = blockIdx.x * 256 + threadIdx.x;
    bool f32 = (*dt != 0);
    const void* src; int off;
    if      (i < 16384) { src = wl0; off = i; }
    else if (i < 32768) { src = wr0; off = i - 16384; }
    else if (i < 49152) { src = wl1; off = i - 32768; }
    else if (i < 65536) { src = wr1; off = i - 49152; }
    else if (i < 65664) { src = b0;  off = i - 65536; }
    else if (i < 65792) { src = b1;  off = i - 65664; }
    else return;
    out[i] = f32 ? f2bf(((const float*)src)[off]) : ((const uint16_t*)src)[off];
}

// ---------- CSR build ----------
__global__ void zero_cnt_k(int* cnt, int n) {
    int i = blockIdx.x * 256 + threadIdx.x;
    if (i < n) cnt[i] = 0;
}

__global__ void count_k(const int* dst, int* cnt, int E, int n) {
    int e = blockIdx.x * 256 + threadIdx.x;
    if (e < E) {
        int d = dst[e];
        if ((unsigned)d < (unsigned)n) atomicAdd(&cnt[d], 1);
    }
}

// parallel scan, 3 phases (replaces the 302 µs single-block scan)
__global__ void scan1_k(const int* cnt, int* bsum, int n) {
    __shared__ int wt[4];
    int t = threadIdx.x, lane = t & 63, wv = t >> 6;
    int i = blockIdx.x * 256 + t;
    int v = (i < n) ? cnt[i] : 0;
    for (int off = 32; off; off >>= 1) v += __shfl_down(v, off);
    if (lane == 0) wt[wv] = v;
    __syncthreads();
    if (t == 0) bsum[blockIdx.x] = wt[0] + wt[1] + wt[2] + wt[3];
}

__global__ void scan2_k(const int* bsum, int* boff, int* row_n, int nb) {
    __shared__ int wt[4];
    __shared__ int carry_s;
    int t = threadIdx.x, lane = t & 63, wv = t >> 6;
    if (t == 0) carry_s = 0;
    __syncthreads();
    for (int base = 0; base < nb; base += 256) {
        int i = base + t;
        int c = (i < nb) ? bsum[i] : 0;
        int v = c;
        for (int off = 1; off < 64; off <<= 1) {
            int u = __shfl_up(v, off);
            if (lane >= off) v += u;
        }
        if (lane == 63) wt[wv] = v;
        __syncthreads();
        int woff = 0;
        for (int w = 0; w < wv; ++w) woff += wt[w];
        int total = wt[0] + wt[1] + wt[2] + wt[3];
        int carry = carry_s;
        if (i < nb) boff[i] = carry + woff + (v - c);
        __syncthreads();
        if (t == 0) carry_s = carry + total;
        __syncthreads();
    }
    if (t == 0) *row_n = carry_s;
}

__global__ void scan3_k(const int* cnt, const int* boff, int* row_start,
                        int* cursor, float* inv_deg, int n) {
    __shared__ int wt[4];
    int t = threadIdx.x, lane = t & 63, wv = t >> 6;
    int i = blockIdx.x * 256 + t;
    int c = (i < n) ? cnt[i] : 0;
    int v = c;
    for (int off = 1; off < 64; off <<= 1) {
        int u = __shfl_up(v, off);
        if (lane >= off) v += u;
    }
    if (lane == 63) wt[wv] = v;
    __syncthreads();
    int woff = 0;
    for (int w = 0; w < wv; ++w) woff += wt[w];
    if (i < n) {
        int rs = boff[blockIdx.x] + woff + (v - c);
        row_start[i] = rs;
        cursor[i] = rs;
        inv_deg[i] = 1.0f / fmaxf((float)c, 1.0f);
    }
}

__global__ void fill_k(const int* src, const int* dst, int* cursor,
                       int* csr_src, int E, int n) {
    int e = blockIdx.x * 256 + threadIdx.x;
    if (e < E) {
        int d = dst[e];
        if ((unsigned)d < (unsigned)n) {
            int pos = atomicAdd(&cursor[d], 1);
            csr_src[pos] = src[e];
        }
    }
}

// ---------- mean aggregation: one wave per dst node, bf16 in/out ----------
__global__ void agg_k(const uint16_t* feat, const int* csr_src,
                      const int* row_start, const float* inv_deg,
                      uint16_t* A, int n) {
    int wave = threadIdx.x >> 6, lane = threadIdx.x & 63;
    int node = blockIdx.x * 4 + wave;
    if (node >= n) return;
    int e0 = row_start[node], e1 = row_start[node + 1];
    const uint32_t* fp = (const uint32_t*)feat;
    float ax = 0.f, ay = 0.f;
    for (int e = e0; e < e1; ++e) {
        int s = csr_src[e];
        if ((unsigned)s >= (unsigned)n) continue;
        uint32_t u = fp[(size_t)s * 64 + lane];
        ax += bf2f((uint16_t)u);
        ay += bf2f((uint16_t)(u >> 16));
    }
    float sc = inv_deg[node];
    uint32_t w = (uint32_t)f2bf(ax * sc) | ((uint32_t)f2bf(ay * sc) << 16);
    ((uint32_t*)A)[(size_t)node * 64 + lane] = w;
}

// ---------- MFMA dense: Y = X@W^T (+bias, +root, relu) ----------
// One wave per 16-node strip; 8 n-tiles x 4 K-steps of mfma_f32_16x16x32_bf16.
// Verified layouts (guide §3): A[m=lane&15][k=(lane>>4)*8+j]; B mirrors with
// n=lane&15 (we need B[k][n]=W[n][k] -> lane reads 8 consecutive k of W row n);
// C/D: col=lane&15, row=(lane>>4)*4+reg.
// In-place safe for X==Y: all A-frag loads drain before first epilogue store.
__global__ void mfma_dense_k(const uint16_t* __restrict__ X,
                             const uint16_t* __restrict__ Wb,   // bf16 [128][128]
                             const uint16_t* __restrict__ bias, // bf16, may be null
                             uint16_t* __restrict__ Hroot,      // fused mode if non-null
                             uint16_t* __restrict__ Y,          // plain mode
                             int n) {
    const int lane = threadIdx.x & 63;
    const int wv = threadIdx.x >> 6;
    const int m0 = blockIdx.x * 64 + wv * 16;
    if (m0 >= n) return;
    const int row16 = lane & 15, quad = lane >> 4;
    int mrow = m0 + row16;
    int mload = (mrow < n) ? mrow : (n - 1);   // clamp; bogus rows masked at store
    v8s a[4];
    const uint16_t* xr = X + (size_t)mload * DH + quad * 8;
#pragma unroll
    for (int kt = 0; kt < 4; ++kt)
        a[kt] = *(const v8s*)(xr + kt * 32);

#pragma unroll
    for (int nt = 0; nt < 8; ++nt) {
        v4f acc = {0.f, 0.f, 0.f, 0.f};
        const uint16_t* wr = Wb + (size_t)(nt * 16 + row16) * DH + quad * 8;
#pragma unroll
        for (int kt = 0; kt < 4; ++kt) {
            v8s b = *(const v8s*)(wr + kt * 32);
            acc = __builtin_amdgcn_mfma_f32_16x16x32_bf16(a[kt], b, acc, 0, 0, 0);
        }
        int o = nt * 16 + row16;
        float bo = (bias != nullptr) ? bf2f(bias[o]) : 0.0f;
#pragma unroll
        for (int r = 0; r < 4; ++r) {
            int m = m0 + quad * 4 + r;
            if (m < n) {
                size_t idx = (size_t)m * DH + o;
                float v = acc[r] + bo;
                if (Hroot != nullptr) {
                    v += bf2f(Hroot[idx]);
                    Hroot[idx] = f2bf(fmaxf(v, 0.0f));
                } else {
                    Y[idx] = f2bf(v);
                }
            }
        }
    }
}

// ---------- layer 2: transform-then-aggregate (unchanged, passed) ----------
__global__ void transform2_k(const uint16_t* H, const void* Wl2,
                             const void* Wr2, const int* wdt,
                             float* T, float* Q, int n) {
    int wave = threadIdx.x >> 6, lane = threadIdx.x & 63;
    int node = blockIdx.x * 4 + wave;
    if (node >= n) return;
    bool f32 = (*wdt != 0);
    const uint16_t* h = H + (size_t)node * DH;
    float h0 = bf2f(h[lane]), h1 = bf2f(h[lane + 64]);
    float p0 = h0 * loadf(Wl2, lane, f32)       + h1 * loadf(Wl2, 64 + lane, f32);
    float p1 = h0 * loadf(Wl2, 128 + lane, f32) + h1 * loadf(Wl2, 192 + lane, f32);
    float q0 = h0 * loadf(Wr2, lane, f32)       + h1 * loadf(Wr2, 64 + lane, f32);
    float q1 = h0 * loadf(Wr2, 128 + lane, f32) + h1 * loadf(Wr2, 192 + lane, f32);
    for (int off = 32; off; off >>= 1) {
        p0 += __shfl_down(p0, off);
        p1 += __shfl_down(p1, off);
        q0 += __shfl_down(q0, off);
        q1 += __shfl_down(q1, off);
    }
    if (lane == 0) {
        T[(size_t)node * 2]     = p0;
        T[(size_t)node * 2 + 1] = p1;
        Q[(size_t)node * 2]     = q0;
        Q[(size_t)node * 2 + 1] = q1;
    }
}

// ---------- final: 2-wide CSR gather + log_softmax, fp32 out (unchanged) ----------
__global__ void final_k(const float* T, const float* Q, const int* row_start,
                        const int* csr_src, const float* inv_deg,
                        const void* b2, const int* wdt, float* out, int n) {
    int i = blockIdx.x * 256 + threadIdx.x;
    if (i >= n) return;
    bool f32 = (*wdt != 0);
    int e0 = row_start[i], e1 = row_start[i + 1];
    float s0 = 0.f, s1 = 0.f;
    for (int e = e0; e < e1; ++e) {
        int j = csr_src[e];
        if ((unsigned)j >= (unsigned)n) continue;
        s0 += T[(size_t)j * 2];
        s1 += T[(size_t)j * 2 + 1];
    }
    float sc = inv_deg[i];
    float l0 = s0 * sc + loadf(b2, 0, f32) + Q[(size_t)i * 2];
    float l1 = s1 * sc + loadf(b2, 1, f32) + Q[(size_t)i * 2 + 1];
    float m = fmaxf(l0, l1);
    float lse = m + logf(expf(l0 - m) + expf(l1 - m));
    out[(size_t)i * 2]     = l0 - lse;
    out[(size_t)i * 2 + 1] = l1 - lse;
}

extern "C" void kernel_launch(void* const* d_in, const int* in_sizes, int n_in,
                              void* d_out, int out_size, void* d_ws, size_t ws_size,
                              hipStream_t stream) {
    int ix, iwl0, ib0, iwr0, iwl1, ib1, iwr1, iwl2, ib2, iwr2, iesrc, iedst;
    if (in_sizes[0] < 100000) {  // sorted-keys fallback
        ib0 = 0; ib1 = 1; ib2 = 2; iedst = 3; iesrc = 4;
        iwl0 = 5; iwl1 = 6; iwl2 = 7; iwr0 = 8; iwr1 = 9; iwr2 = 10; ix = 11;
    } else {                     // dict-insertion order (confirmed by R7 pass)
        ix = 0; iwl0 = 1; ib0 = 2; iwr0 = 3; iwl1 = 4; ib1 = 5;
        iwr1 = 6; iwl2 = 7; ib2 = 8; iwr2 = 9; iesrc = 10; iedst = 11;
    }
    const void* x   = d_in[ix];
    const void* wl0 = d_in[iwl0];
    const void* b0  = d_in[ib0];
    const void* wr0 = d_in[iwr0];
    const void* wl1 = d_in[iwl1];
    const void* b1  = d_in[ib1];
    const void* wr1 = d_in[iwr1];
    const void* wl2 = d_in[iwl2];
    const void* b2  = d_in[ib2];
    const void* wr2 = d_in[iwr2];
    const int* esrc = (const int*)d_in[iesrc];
    const int* edst = (const int*)d_in[iedst];
    const int N = out_size / 2;
    const int E = in_sizes[iesrc];
    (void)n_in; (void)ws_size;

    char* ws = (char*)d_ws;
    size_t off = 0;
    auto carve = [&](size_t bytes) -> char* {
        char* p = ws + off;
        off = (off + bytes + 255) & ~(size_t)255;
        return p;
    };
    int gN = (N + 255) / 256;               // also #scan blocks
    int* dtf        = (int*)   carve(256);
    int* cnt        = (int*)   carve((size_t)N * 4);
    int* row_start  = (int*)   carve((size_t)(N + 1) * 4);
    int* cursor     = (int*)   carve((size_t)N * 4);
    float* inv_deg  = (float*) carve((size_t)N * 4);
    int* bsum       = (int*)   carve((size_t)gN * 4);
    int* boff       = (int*)   carve((size_t)gN * 4);
    int* csr_src    = (int*)   carve((size_t)E * 4);
    uint16_t* A16   = (uint16_t*)carve((size_t)N * DH * 2);
    uint16_t* H16   = (uint16_t*)carve((size_t)N * DH * 2);
    uint16_t* xb    = (uint16_t*)carve((size_t)N * DH * 2);
    uint16_t* wcvt  = (uint16_t*)carve(65792 * 2);
    float* T        = (float*) carve((size_t)N * 2 * 4);
    float* Q        = (float*) carve((size_t)N * 2 * 4);
    uint16_t* wl0b = wcvt;
    uint16_t* wr0b = wcvt + 16384;
    uint16_t* wl1b = wcvt + 32768;
    uint16_t* wr1b = wcvt + 49152;
    uint16_t* b0b  = wcvt + 65536;
    uint16_t* b1b  = wcvt + 65664;

    int gE = (E + 255) / 256;
    int ga = (N + 3) / 4;
    int gd = (N + 63) / 64;
    int gx = (N * DH + 255) / 256;

    // dtype flag + normalize dense-path operands to bf16
    detect_k<<<1, 64, 0, stream>>>((const uint32_t*)wl0, dtf);
    cvt_k<<<gx, 256, 0, stream>>>(x, dtf, xb, N * DH);
    cvtw_k<<<(65792 + 255) / 256, 256, 0, stream>>>(wl0, wr0, wl1, wr1, b0, b1, dtf, wcvt);

    // CSR build (parallel scan)
    zero_cnt_k<<<gN, 256, 0, stream>>>(cnt, N);
    count_k<<<gE, 256, 0, stream>>>(edst, cnt, E, N);
    scan1_k<<<gN, 256, 0, stream>>>(cnt, bsum, N);
    scan2_k<<<1, 256, 0, stream>>>(bsum, boff, &row_start[N], gN);
    scan3_k<<<gN, 256, 0, stream>>>(cnt, boff, row_start, cursor, inv_deg, N);
    fill_k<<<gE, 256, 0, stream>>>(esrc, edst, cursor, csr_src, E, N);

    // layer 0: A = agg(xb); H = xb@Wr0^T; H = relu(A@Wl0^T + b0 + H)
    agg_k<<<ga, 256, 0, stream>>>(xb, csr_src, row_start, inv_deg, A16, N);
    mfma_dense_k<<<gd, 256, 0, stream>>>(xb, wr0b, nullptr, nullptr, H16, N);
    mfma_dense_k<<<gd, 256, 0, stream>>>(A16, wl0b, b0b, H16, nullptr, N);

    // layer 1: A = agg(H); H = H@Wr1^T (in-place); H = relu(A@Wl1^T + b1 + H)
    agg_k<<<ga, 256, 0, stream>>>(H16, csr_src, row_start, inv_deg, A16, N);
    mfma_dense_k<<<gd, 256, 0, stream>>>(H16, wr1b, nullptr, nullptr, H16, N);
    mfma_dense_k<<<gd, 256, 0, stream>>>(A16, wl1b, b1b, H16, nullptr, N);

    // layer 2: transform-then-aggregate + log_softmax (fp32 out)
    transform2_k<<<ga, 256, 0, stream>>>(H16, wl2, wr2, dtf, T, Q, N);
    final_k<<<gN, 256, 0, stream>>>(T, Q, row_start, csr_src, inv_deg,
                                    b2, dtf, (float*)d_out, N);
}

// Round 9
// 636.429 us; speedup vs baseline: 2.5081x; 1.3101x over previous
//
#include <hip/hip_runtime.h>
#include <stdint.h>
#include <stddef.h>

#define DH 128

typedef short v8s __attribute__((ext_vector_type(8)));
typedef float v4f __attribute__((ext_vector_type(4)));

static __device__ __forceinline__ float bf2f(uint16_t h) {
    union { uint32_t i; float f; } u; u.i = ((uint32_t)h) << 16; return u.f;
}
static __device__ __forceinline__ uint16_t f2bf(float f) {
    union { float f; uint32_t i; } u; u.f = f;
    uint32_t r = u.i + 0x7fffu + ((u.i >> 16) & 1u);  // RNE
    return (uint16_t)(r >> 16);
}
static __device__ __forceinline__ float loadf(const void* p, size_t i, bool f32) {
    return f32 ? ((const float*)p)[i] : bf2f(((const uint16_t*)p)[i]);
}

// ---------- init: zero cnt + dtype detect (fused) ----------
__global__ void init_k(const uint32_t* w, int* flag, int* cnt, int n) {
    int i = blockIdx.x * 256 + threadIdx.x;
    if (i < n) cnt[i] = 0;
    if (blockIdx.x == 0 && threadIdx.x < 64) {
        int t = threadIdx.x;
        int hits = 0;
        for (int k = 0; k < 4; ++k) {
            uint32_t u = w[t * 4 + k];
            int e = (u >> 7) & 0xFF;
            hits += (e >= 100 && e <= 130) ? 1 : 0;
        }
        for (int off = 32; off; off >>= 1) hits += __shfl_down(hits, off);
        if (t == 0) *flag = (hits >= 128) ? 0 : 1;   // 0 = bf16, 1 = fp32
    }
}

// ---------- convert x + 4 weights + 2 biases to bf16 (fused) ----------
__global__ void cvtall_k(const void* x, const void* wl0, const void* wr0,
                         const void* wl1, const void* wr1, const void* b0,
                         const void* b1, const int* dt, uint16_t* xb,
                         uint16_t* wcvt, int nx) {
    int i = blockIdx.x * 256 + threadIdx.x;
    bool f32 = (*dt != 0);
    if (i < nx) {
        xb[i] = f32 ? f2bf(((const float*)x)[i]) : ((const uint16_t*)x)[i];
        return;
    }
    int j = i - nx;
    const void* src; int off;
    if      (j < 16384) { src = wl0; off = j; }
    else if (j < 32768) { src = wr0; off = j - 16384; }
    else if (j < 49152) { src = wl1; off = j - 32768; }
    else if (j < 65536) { src = wr1; off = j - 49152; }
    else if (j < 65664) { src = b0;  off = j - 65536; }
    else if (j < 65792) { src = b1;  off = j - 65664; }
    else return;
    wcvt[j] = f32 ? f2bf(((const float*)src)[off]) : ((const uint16_t*)src)[off];
}

// ---------- CSR build ----------
__global__ void count_k(const int* dst, int* cnt, int E, int n) {
    int e = blockIdx.x * 256 + threadIdx.x;
    if (e < E) {
        int d = dst[e];
        if ((unsigned)d < (unsigned)n) atomicAdd(&cnt[d], 1);
    }
}

__global__ void scan1_k(const int* cnt, int* bsum, int n) {
    __shared__ int wt[4];
    int t = threadIdx.x, lane = t & 63, wv = t >> 6;
    int i = blockIdx.x * 256 + t;
    int v = (i < n) ? cnt[i] : 0;
    for (int off = 32; off; off >>= 1) v += __shfl_down(v, off);
    if (lane == 0) wt[wv] = v;
    __syncthreads();
    if (t == 0) bsum[blockIdx.x] = wt[0] + wt[1] + wt[2] + wt[3];
}

__global__ void scan2_k(const int* bsum, int* boff, int* row_n, int nb) {
    __shared__ int wt[4];
    __shared__ int carry_s;
    int t = threadIdx.x, lane = t & 63, wv = t >> 6;
    if (t == 0) carry_s = 0;
    __syncthreads();
    for (int base = 0; base < nb; base += 256) {
        int i = base + t;
        int c = (i < nb) ? bsum[i] : 0;
        int v = c;
        for (int off = 1; off < 64; off <<= 1) {
            int u = __shfl_up(v, off);
            if (lane >= off) v += u;
        }
        if (lane == 63) wt[wv] = v;
        __syncthreads();
        int woff = 0;
        for (int w = 0; w < wv; ++w) woff += wt[w];
        int total = wt[0] + wt[1] + wt[2] + wt[3];
        int carry = carry_s;
        if (i < nb) boff[i] = carry + woff + (v - c);
        __syncthreads();
        if (t == 0) carry_s = carry + total;
        __syncthreads();
    }
    if (t == 0) *row_n = carry_s;
}

__global__ void scan3_k(const int* cnt, const int* boff, int* row_start,
                        int* cursor, float* inv_deg, int n) {
    __shared__ int wt[4];
    int t = threadIdx.x, lane = t & 63, wv = t >> 6;
    int i = blockIdx.x * 256 + t;
    int c = (i < n) ? cnt[i] : 0;
    int v = c;
    for (int off = 1; off < 64; off <<= 1) {
        int u = __shfl_up(v, off);
        if (lane >= off) v += u;
    }
    if (lane == 63) wt[wv] = v;
    __syncthreads();
    int woff = 0;
    for (int w = 0; w < wv; ++w) woff += wt[w];
    if (i < n) {
        int rs = boff[blockIdx.x] + woff + (v - c);
        row_start[i] = rs;
        cursor[i] = rs;
        inv_deg[i] = 1.0f / fmaxf((float)c, 1.0f);
    }
}

__global__ void fill_k(const int* src, const int* dst, int* cursor,
                       int* csr_src, int E, int n) {
    int e = blockIdx.x * 256 + threadIdx.x;
    if (e < E) {
        int d = dst[e];
        if ((unsigned)d < (unsigned)n) {
            int pos = atomicAdd(&cursor[d], 1);
            csr_src[pos] = src[e];
        }
    }
}

// ---------- mean aggregation v2: one wave per node, 4 edges/iteration ----------
// lane = (sub<<4)|seg: sub in [0,4) = edge slot, seg in [0,16) = 16-byte row
// segment. Each iteration the wave gathers 4 full 256 B rows (uint4/lane).
// Cross-reduce over sub at the end; lanes 0-15 write the 256 B result row.
__global__ void agg_k(const uint16_t* feat, const int* csr_src,
                      const int* row_start, const float* inv_deg,
                      uint16_t* A, int n) {
    int wave = threadIdx.x >> 6, lane = threadIdx.x & 63;
    int node = blockIdx.x * 4 + wave;
    if (node >= n) return;
    int seg = lane & 15, sub = lane >> 4;
    int e0 = row_start[node], e1 = row_start[node + 1];
    const uint4* fp = (const uint4*)feat;     // 16 uint4 per row
    float acc[8] = {0.f,0.f,0.f,0.f,0.f,0.f,0.f,0.f};
    for (int e = e0 + sub; e < e1; e += 4) {
        int s = csr_src[e];
        if ((unsigned)s >= (unsigned)n) continue;
        uint4 u = fp[(size_t)s * 16 + seg];
        acc[0] += bf2f((uint16_t)u.x); acc[1] += bf2f((uint16_t)(u.x >> 16));
        acc[2] += bf2f((uint16_t)u.y); acc[3] += bf2f((uint16_t)(u.y >> 16));
        acc[4] += bf2f((uint16_t)u.z); acc[5] += bf2f((uint16_t)(u.z >> 16));
        acc[6] += bf2f((uint16_t)u.w); acc[7] += bf2f((uint16_t)(u.w >> 16));
    }
#pragma unroll
    for (int i = 0; i < 8; ++i) {
        acc[i] += __shfl_down(acc[i], 32);
        acc[i] += __shfl_down(acc[i], 16);
    }
    if (sub == 0) {
        float sc = inv_deg[node];
        uint4 o;
        o.x = (uint32_t)f2bf(acc[0] * sc) | ((uint32_t)f2bf(acc[1] * sc) << 16);
        o.y = (uint32_t)f2bf(acc[2] * sc) | ((uint32_t)f2bf(acc[3] * sc) << 16);
        o.z = (uint32_t)f2bf(acc[4] * sc) | ((uint32_t)f2bf(acc[5] * sc) << 16);
        o.w = (uint32_t)f2bf(acc[6] * sc) | ((uint32_t)f2bf(acc[7] * sc) << 16);
        ((uint4*)A)[(size_t)node * 16 + seg] = o;
    }
}

// ---------- fused dual MFMA dense: H = relu(X@Wr^T + A@Wl^T + b) ----------
// One wave per 16-node strip; per n-tile, 8 chained MFMAs (4 K-steps x 2
// operands) into one accumulator. No H read-modify round-trip. In-place safe
// for X==H (wave reads/writes only its own rows; frags loaded before stores).
__global__ void dense2_k(const uint16_t* __restrict__ X,
                         const uint16_t* __restrict__ A,
                         const uint16_t* __restrict__ Wr,
                         const uint16_t* __restrict__ Wl,
                         const uint16_t* __restrict__ bias,
                         uint16_t* __restrict__ H, int n) {
    const int lane = threadIdx.x & 63;
    const int wv = threadIdx.x >> 6;
    const int m0 = blockIdx.x * 64 + wv * 16;
    if (m0 >= n) return;
    const int row16 = lane & 15, quad = lane >> 4;
    int mrow = m0 + row16;
    int mload = (mrow < n) ? mrow : (n - 1);
    v8s ax[4], aa[4];
    const uint16_t* xr = X + (size_t)mload * DH + quad * 8;
    const uint16_t* ar = A + (size_t)mload * DH + quad * 8;
#pragma unroll
    for (int kt = 0; kt < 4; ++kt) {
        ax[kt] = *(const v8s*)(xr + kt * 32);
        aa[kt] = *(const v8s*)(ar + kt * 32);
    }
#pragma unroll
    for (int nt = 0; nt < 8; ++nt) {
        v4f acc = {0.f, 0.f, 0.f, 0.f};
        const uint16_t* wrr = Wr + (size_t)(nt * 16 + row16) * DH + quad * 8;
        const uint16_t* wlr = Wl + (size_t)(nt * 16 + row16) * DH + quad * 8;
#pragma unroll
        for (int kt = 0; kt < 4; ++kt) {
            v8s br = *(const v8s*)(wrr + kt * 32);
            acc = __builtin_amdgcn_mfma_f32_16x16x32_bf16(ax[kt], br, acc, 0, 0, 0);
            v8s bl = *(const v8s*)(wlr + kt * 32);
            acc = __builtin_amdgcn_mfma_f32_16x16x32_bf16(aa[kt], bl, acc, 0, 0, 0);
        }
        int o = nt * 16 + row16;
        float bo = bf2f(bias[o]);
#pragma unroll
        for (int r = 0; r < 4; ++r) {
            int m = m0 + quad * 4 + r;
            if (m < n)
                H[(size_t)m * DH + o] = f2bf(fmaxf(acc[r] + bo, 0.0f));
        }
    }
}

// ---------- layer 2: transform-then-aggregate ----------
__global__ void transform2_k(const uint16_t* H, const void* Wl2,
                             const void* Wr2, const int* wdt,
                             float* T, float* Q, int n) {
    int wave = threadIdx.x >> 6, lane = threadIdx.x & 63;
    int node = blockIdx.x * 4 + wave;
    if (node >= n) return;
    bool f32 = (*wdt != 0);
    const uint16_t* h = H + (size_t)node * DH;
    float h0 = bf2f(h[lane]), h1 = bf2f(h[lane + 64]);
    float p0 = h0 * loadf(Wl2, lane, f32)       + h1 * loadf(Wl2, 64 + lane, f32);
    float p1 = h0 * loadf(Wl2, 128 + lane, f32) + h1 * loadf(Wl2, 192 + lane, f32);
    float q0 = h0 * loadf(Wr2, lane, f32)       + h1 * loadf(Wr2, 64 + lane, f32);
    float q1 = h0 * loadf(Wr2, 128 + lane, f32) + h1 * loadf(Wr2, 192 + lane, f32);
    for (int off = 32; off; off >>= 1) {
        p0 += __shfl_down(p0, off);
        p1 += __shfl_down(p1, off);
        q0 += __shfl_down(q0, off);
        q1 += __shfl_down(q1, off);
    }
    if (lane == 0) {
        T[(size_t)node * 2]     = p0;
        T[(size_t)node * 2 + 1] = p1;
        Q[(size_t)node * 2]     = q0;
        Q[(size_t)node * 2 + 1] = q1;
    }
}

// ---------- final: 2-wide CSR gather + log_softmax, fp32 out ----------
__global__ void final_k(const float* T, const float* Q, const int* row_start,
                        const int* csr_src, const float* inv_deg,
                        const void* b2, const int* wdt, float* out, int n) {
    int i = blockIdx.x * 256 + threadIdx.x;
    if (i >= n) return;
    bool f32 = (*wdt != 0);
    int e0 = row_start[i], e1 = row_start[i + 1];
    float s0 = 0.f, s1 = 0.f;
    for (int e = e0; e < e1; ++e) {
        int j = csr_src[e];
        if ((unsigned)j >= (unsigned)n) continue;
        s0 += T[(size_t)j * 2];
        s1 += T[(size_t)j * 2 + 1];
    }
    float sc = inv_deg[i];
    float l0 = s0 * sc + loadf(b2, 0, f32) + Q[(size_t)i * 2];
    float l1 = s1 * sc + loadf(b2, 1, f32) + Q[(size_t)i * 2 + 1];
    float m = fmaxf(l0, l1);
    float lse = m + logf(expf(l0 - m) + expf(l1 - m));
    out[(size_t)i * 2]     = l0 - lse;
    out[(size_t)i * 2 + 1] = l1 - lse;
}

extern "C" void kernel_launch(void* const* d_in, const int* in_sizes, int n_in,
                              void* d_out, int out_size, void* d_ws, size_t ws_size,
                              hipStream_t stream) {
    int ix, iwl0, ib0, iwr0, iwl1, ib1, iwr1, iwl2, ib2, iwr2, iesrc, iedst;
    if (in_sizes[0] < 100000) {  // sorted-keys fallback
        ib0 = 0; ib1 = 1; ib2 = 2; iedst = 3; iesrc = 4;
        iwl0 = 5; iwl1 = 6; iwl2 = 7; iwr0 = 8; iwr1 = 9; iwr2 = 10; ix = 11;
    } else {                     // dict-insertion order (confirmed by R7/R8 pass)
        ix = 0; iwl0 = 1; ib0 = 2; iwr0 = 3; iwl1 = 4; ib1 = 5;
        iwr1 = 6; iwl2 = 7; ib2 = 8; iwr2 = 9; iesrc = 10; iedst = 11;
    }
    const void* x   = d_in[ix];
    const void* wl0 = d_in[iwl0];
    const void* b0  = d_in[ib0];
    const void* wr0 = d_in[iwr0];
    const void* wl1 = d_in[iwl1];
    const void* b1  = d_in[ib1];
    const void* wr1 = d_in[iwr1];
    const void* wl2 = d_in[iwl2];
    const void* b2  = d_in[ib2];
    const void* wr2 = d_in[iwr2];
    const int* esrc = (const int*)d_in[iesrc];
    const int* edst = (const int*)d_in[iedst];
    const int N = out_size / 2;
    const int E = in_sizes[iesrc];
    (void)n_in; (void)ws_size;

    char* ws = (char*)d_ws;
    size_t off = 0;
    auto carve = [&](size_t bytes) -> char* {
        char* p = ws + off;
        off = (off + bytes + 255) & ~(size_t)255;
        return p;
    };
    int gN = (N + 255) / 256;
    int* dtf        = (int*)   carve(256);
    int* cnt        = (int*)   carve((size_t)N * 4);
    int* row_start  = (int*)   carve((size_t)(N + 1) * 4);
    int* cursor     = (int*)   carve((size_t)N * 4);
    float* inv_deg  = (float*) carve((size_t)N * 4);
    int* bsum       = (int*)   carve((size_t)gN * 4);
    int* boff       = (int*)   carve((size_t)gN * 4);
    int* csr_src    = (int*)   carve((size_t)E * 4);
    uint16_t* A16   = (uint16_t*)carve((size_t)N * DH * 2);
    uint16_t* H16   = (uint16_t*)carve((size_t)N * DH * 2);
    uint16_t* xb    = (uint16_t*)carve((size_t)N * DH * 2);
    uint16_t* wcvt  = (uint16_t*)carve(65792 * 2);
    float* T        = (float*) carve((size_t)N * 2 * 4);
    float* Q        = (float*) carve((size_t)N * 2 * 4);
    uint16_t* wl0b = wcvt;
    uint16_t* wr0b = wcvt + 16384;
    uint16_t* wl1b = wcvt + 32768;
    uint16_t* wr1b = wcvt + 49152;
    uint16_t* b0b  = wcvt + 65536;
    uint16_t* b1b  = wcvt + 65664;

    int gE = (E + 255) / 256;
    int ga = (N + 3) / 4;
    int gd = (N + 63) / 64;
    int nx = N * DH;
    int gc = (nx + 65792 + 255) / 256;

    init_k<<<gN, 256, 0, stream>>>((const uint32_t*)wl0, dtf, cnt, N);
    cvtall_k<<<gc, 256, 0, stream>>>(x, wl0, wr0, wl1, wr1, b0, b1, dtf, xb, wcvt, nx);

    // CSR build (parallel scan)
    count_k<<<gE, 256, 0, stream>>>(edst, cnt, E, N);
    scan1_k<<<gN, 256, 0, stream>>>(cnt, bsum, N);
    scan2_k<<<1, 256, 0, stream>>>(bsum, boff, &row_start[N], gN);
    scan3_k<<<gN, 256, 0, stream>>>(cnt, boff, row_start, cursor, inv_deg, N);
    fill_k<<<gE, 256, 0, stream>>>(esrc, edst, cursor, csr_src, E, N);

    // layer 0: A = agg(xb); H = relu(xb@Wr0^T + A@Wl0^T + b0)
    agg_k<<<ga, 256, 0, stream>>>(xb, csr_src, row_start, inv_deg, A16, N);
    dense2_k<<<gd, 256, 0, stream>>>(xb, A16, wr0b, wl0b, b0b, H16, N);

    // layer 1: A = agg(H); H = relu(H@Wr1^T + A@Wl1^T + b1)  (in-place)
    agg_k<<<ga, 256, 0, stream>>>(H16, csr_src, row_start, inv_deg, A16, N);
    dense2_k<<<gd, 256, 0, stream>>>(H16, A16, wr1b, wl1b, b1b, H16, N);

    // layer 2: transform-then-aggregate + log_softmax (fp32 out)
    transform2_k<<<ga, 256, 0, stream>>>(H16, wl2, wr2, dtf, T, Q, N);
    final_k<<<gN, 256, 0, stream>>>(T, Q, row_start, csr_src, inv_deg,
                                    b2, dtf, (float*)d_out, N);
}